// Round 9
// baseline (438.025 us; speedup 1.0000x reference)
//
#include <hip/hip_runtime.h>

// ---------------------------------------------------------------------------
// hipcc defaults to -ffp-contract=fast; plain-operator float math gets fused
// into FMAs unless contraction is off. (Proved in R7->R8: identical source
// "orderings" R1/R2/R5 produced bit-identical absmax; turning contract off
// moved it.) __builtin_fmaf is a real fma op and is unaffected by the pragma,
// so explicit mixing below executes exactly as written.
// ---------------------------------------------------------------------------
#pragma clang fp contract(off)

#define BQ_B 8
#define BQ_N 8192
#define BQ_M 2048
#define BQ_C 64
#define BQ_K 32

// ---------------------------------------------------------------------------
// Fused kernel (structure frozen since R7; collector verified against a
// sequential scan in R6; gather path verified fresh in R7).
//
// Decision-function ledger (executed code, not source intent):
//   all-FMA expanded (R1/R2/R5)      -> absmax 5.578125
//   exact f64 / fp32-direct (R3/R4)  -> absmax 5.875
//   sequential-rn expanded (R8)      -> absmax 5.203125
// This round — the hybrid BOTH plausible reference pipelines converge on
// (numpy + BLAS einsum, or XLA-CPU + Eigen dot_general):
//   c2  = (cx*cx + cy*cy) + cz*cz            [seq rn]
//   p2  = (x*x + y*y) + z*z                  [seq rn]
//   dot = fma(cz,z, fma(cy,y, cx*x))         [ascending FMA chain, k=3 sgemm]
//   d2  = (c2 + p2) - 2*dot                  [rn, rn]
//   hit = d2 < 0.01f                         [strict]
// ---------------------------------------------------------------------------
__global__ __launch_bounds__(256) void bq_fused(
    const float* __restrict__ pts, const float* __restrict__ ctrs,
    const float* __restrict__ feats, float* __restrict__ out)
{
#pragma clang fp contract(off)
    __shared__ int wlist[4][BQ_K];

    const int tid  = threadIdx.x;
    const int lane = tid & 63;
    const int wave = tid >> 6;

    const int cid = blockIdx.x * 4 + wave;     // global center id
    const int b   = cid >> 11;                 // / BQ_M
    const int m   = cid & (BQ_M - 1);

    const float cx = ctrs[(b * 3 + 0) * BQ_M + m];
    const float cy = ctrs[(b * 3 + 1) * BQ_M + m];
    const float cz = ctrs[(b * 3 + 2) * BQ_M + m];
    const float c2 = (cx * cx + cy * cy) + cz * cz;   // sequential rn

    const float* px = pts + (size_t)b * 3 * BQ_N;
    const float* py = px + BQ_N;
    const float* pz = py + BQ_N;

    // ---- phase 1: ordered first-K scan ----
    int count = 0;
    for (int n0 = 0; n0 < BQ_N && count < BQ_K; n0 += 64) {
        const int n = n0 + lane;
        const float x = px[n];
        const float y = py[n];
        const float z = pz[n];
        const float p2  = (x * x + y * y) + z * z;            // seq rn
        const float dot = __builtin_fmaf(cz, z,
                          __builtin_fmaf(cy, y, cx * x));     // asc FMA chain
        const float d2  = (c2 + p2) - 2.0f * dot;             // rn, rn
        const bool hit = d2 < 0.01f;                          // strict, f32
        const unsigned long long mask = __ballot(hit);
        if (mask) {
            const int below = (int)__popcll(mask & ((1ull << lane) - 1ull));
            const int pos = count + below;
            if (hit && pos < BQ_K) wlist[wave][pos] = n;
            count += (int)__popcll(mask);
        }
    }

    // ---- phase 2: pad tail with first hit (or 0) ----
    int pad = 0;
    if (count > 0) pad = wlist[wave][0];   // wave-uniform; slot 0 valid
    if (lane >= count && lane < BQ_K) wlist[wave][lane] = pad;
    __syncthreads();

    // ---- phase 3: gather + write (B, 67, M, K) ----
    const int k    = lane & 31;
    const int half = lane >> 5;
    const int i    = wlist[wave][k];       // this wave's k-th neighbor index
    for (int it = 0; it < 34; ++it) {
        const int c = it * 2 + half;       // two channels per iteration
        if (c < 67) {
            float v;
            if (c < 3) {
                v = pts[(size_t)(b * 3 + c) * BQ_N + i] -
                    ctrs[(b * 3 + c) * BQ_M + m];          // single rn sub
            } else {
                v = feats[(size_t)(b * BQ_C + (c - 3)) * BQ_N + i];
            }
            out[((size_t)(b * 67 + c) * BQ_M + m) * BQ_K + k] = v;
        }
    }
}

extern "C" void kernel_launch(void* const* d_in, const int* in_sizes, int n_in,
                              void* d_out, int out_size, void* d_ws, size_t ws_size,
                              hipStream_t stream) {
    const float* pts   = (const float*)d_in[0];   // (B, 3, N)
    const float* ctrs  = (const float*)d_in[1];   // (B, 3, M)
    const float* feats = (const float*)d_in[2];   // (B, C, N)
    float* out = (float*)d_out;                   // (B, 3+C, M, K)

    bq_fused<<<dim3(BQ_B * BQ_M / 4), dim3(256), 0, stream>>>(
        pts, ctrs, feats, out);
}

// Round 10
// 221.123 us; speedup vs baseline: 1.9809x; 1.9809x over previous
//
#include <hip/hip_runtime.h>

// ---------------------------------------------------------------------------
// NUMERICS ARE FROZEN (R9 passed with absmax 0.0). hipcc defaults to
// -ffp-contract=fast, so this pragma is load-bearing: without it the seq-rn
// squares get FMA-fused and decisions flip (R1-R8 saga). Reference-exact
// decision function:
//   c2  = (cx*cx + cy*cy) + cz*cz            [seq rn]
//   p2  = (x*x + y*y) + z*z                  [seq rn]
//   dot = fmaf(cz,z, fmaf(cy,y, cx*x))       [ascending FMA chain]
//   d2  = (c2 + p2) - 2*dot                  [rn, rn]
//   hit = d2 < 0.01f                         [strict]
// ---------------------------------------------------------------------------
#pragma clang fp contract(off)

#define BQ_B 8
#define BQ_N 8192
#define BQ_M 2048
#define BQ_C 64
#define BQ_K 32
#define A_TILE 1024
#define A_WAVES 8

// ---------------------------------------------------------------------------
// Kernel A: index build. R9 was latency-bound: 12 B/lane/pair from L1/L2 with
// VGPR=12 (no ILP) -> ~65 us VALU + serialized loads. Here 8 waves/block share
// LDS-staged (x,y,z,p2) tiles: global traffic /8, p2 hoisted to staging time
// (identical expression + inputs => identical bits), per-pair cost drops to
// 1 ds_read_b128 + ~7 VALU. Collector (ballot + popcount-prefix, wave-uniform
// early exit) is the R6/R9-verified one, untouched.
// ---------------------------------------------------------------------------
__global__ __launch_bounds__(512) void bq_index(
    const float* __restrict__ pts, const float* __restrict__ ctrs,
    int* __restrict__ idx_ws)
{
#pragma clang fp contract(off)
    __shared__ float4 tile[A_TILE];
    __shared__ int wlist[A_WAVES][BQ_K];

    const int tid  = threadIdx.x;
    const int lane = tid & 63;
    const int wave = tid >> 6;

    const int cid = blockIdx.x * A_WAVES + wave;  // 8 centers/block, same b
    const int b   = cid >> 11;
    const int m   = cid & (BQ_M - 1);

    const float cx = ctrs[(b * 3 + 0) * BQ_M + m];
    const float cy = ctrs[(b * 3 + 1) * BQ_M + m];
    const float cz = ctrs[(b * 3 + 2) * BQ_M + m];
    const float c2 = (cx * cx + cy * cy) + cz * cz;   // seq rn (frozen)

    const float* px = pts + (size_t)b * 3 * BQ_N;
    const float* py = px + BQ_N;
    const float* pz = py + BQ_N;

    int count = 0;
    for (int t0 = 0; t0 < BQ_N; t0 += A_TILE) {
        for (int i = tid; i < A_TILE; i += 512) {
            const int n = t0 + i;
            const float x = px[n];
            const float y = py[n];
            const float z = pz[n];
            const float p2 = (x * x + y * y) + z * z;  // seq rn (frozen)
            tile[i] = make_float4(x, y, z, p2);
        }
        __syncthreads();

        if (count < BQ_K) {                       // wave-uniform
            for (int c0 = 0; c0 < A_TILE && count < BQ_K; c0 += 64) {
                const float4 p = tile[c0 + lane];
                const float dot = __builtin_fmaf(cz, p.z,
                                  __builtin_fmaf(cy, p.y, cx * p.x)); // frozen
                const float d2 = (c2 + p.w) - 2.0f * dot;             // frozen
                const bool hit = d2 < 0.01f;                          // frozen
                const unsigned long long mask = __ballot(hit);
                if (mask) {
                    const int below =
                        (int)__popcll(mask & ((1ull << lane) - 1ull));
                    const int pos = count + below;
                    if (hit && pos < BQ_K) wlist[wave][pos] = t0 + c0 + lane;
                    count += (int)__popcll(mask);
                }
            }
        }
        __syncthreads();
    }

    int pad = 0;
    if (count > 0) pad = wlist[wave][0];
    if (lane >= count && lane < BQ_K) wlist[wave][lane] = pad;
    if (lane < BQ_K)
        idx_ws[(size_t)cid * BQ_K + lane] = wlist[wave][lane];
}

// ---------------------------------------------------------------------------
// Kernel B: gather, loop-inverted. One block per (m-tile, channel, batch)
// stages the WHOLE source row (8192 floats = 32 KB) in LDS; the 35M formerly
// scattered global reads become LDS reads (random-bank, ~2-way, nearly free).
// int4 idx loads + float4 stores, both fully coalesced. HBM traffic becomes
// write-dominated (137 MB). Values bit-identical to R9: feature = raw copy,
// coord = single rn sub (contract off).
// ---------------------------------------------------------------------------
__global__ __launch_bounds__(256) void bq_gather_row(
    const float* __restrict__ pts, const float* __restrict__ ctrs,
    const float* __restrict__ feats, const int* __restrict__ idx_ws,
    float* __restrict__ out)
{
#pragma clang fp contract(off)
    __shared__ float row[BQ_N];     // 32 KB
    __shared__ float ctr[BQ_M];     // 8 KB (used only for c < 3)

    const int t  = threadIdx.x;
    const int c  = blockIdx.y;      // 0..66
    const int b  = blockIdx.z;      // 0..7
    const int m0 = blockIdx.x * 512;

    const float* src = (c < 3)
        ? pts   + (size_t)(b * 3 + c) * BQ_N
        : feats + (size_t)(b * BQ_C + (c - 3)) * BQ_N;

    for (int i = t; i < BQ_N / 4; i += 256)
        ((float4*)row)[i] = ((const float4*)src)[i];
    if (c < 3) {
        const float* csrc = ctrs + (b * 3 + c) * BQ_M;
        for (int i = t; i < BQ_M / 4; i += 256)
            ((float4*)ctr)[i] = ((const float4*)csrc)[i];
    }
    __syncthreads();

    const int lc = t >> 3;          // 0..31 local center
    const int k0 = (t & 7) * 4;     // k-group of 4

#pragma unroll 4
    for (int it = 0; it < 16; ++it) {
        const int m = m0 + it * 32 + lc;
        const int4 iv =
            *(const int4*)(idx_ws + (size_t)(b * BQ_M + m) * BQ_K + k0);
        float4 v;
        v.x = row[iv.x];
        v.y = row[iv.y];
        v.z = row[iv.z];
        v.w = row[iv.w];
        if (c < 3) {
            const float cc = ctr[m];
            v.x = v.x - cc;         // single rn sub (frozen, contract off)
            v.y = v.y - cc;
            v.z = v.z - cc;
            v.w = v.w - cc;
        }
        *(float4*)(out + ((size_t)((b * 67 + c) * BQ_M + m)) * BQ_K + k0) = v;
    }
}

extern "C" void kernel_launch(void* const* d_in, const int* in_sizes, int n_in,
                              void* d_out, int out_size, void* d_ws, size_t ws_size,
                              hipStream_t stream) {
    const float* pts   = (const float*)d_in[0];   // (B, 3, N)
    const float* ctrs  = (const float*)d_in[1];   // (B, 3, M)
    const float* feats = (const float*)d_in[2];   // (B, C, N)
    float* out = (float*)d_out;                   // (B, 67, M, K)
    int* idx = (int*)d_ws;                        // (B, M, K) ints = 2 MB
                                                  // (ws round-trip proven in
                                                  //  R1-R6 attribution runs)

    bq_index<<<dim3(BQ_B * BQ_M / A_WAVES), dim3(512), 0, stream>>>(
        pts, ctrs, idx);
    bq_gather_row<<<dim3(BQ_M / 512, 67, BQ_B), dim3(256), 0, stream>>>(
        pts, ctrs, feats, idx, out);
}